// Round 11
// baseline (143.415 us; speedup 1.0000x reference)
//
#include <hip/hip_runtime.h>

#define DEG 32
#define SAW 232   // sA row stride in halves (464 B: 2-way-bank-free on b128 col reads)
#define NT  4     // 128-row tiles per block; grid = 262144/(128*NT) = 512

typedef _Float16 half8 __attribute__((ext_vector_type(8)));
typedef __fp16 fp16x2 __attribute__((ext_vector_type(2)));
typedef float f32x4 __attribute__((ext_vector_type(4)));
typedef int int4v __attribute__((ext_vector_type(4)));

#define EXP2F(x)   __builtin_amdgcn_exp2f(x)
#define SIN_REV(x) __builtin_amdgcn_sinf(x)   // sin(2*pi*x)
#define COS_REV(x) __builtin_amdgcn_cosf(x)   // cos(2*pi*x)
#define RCPF(x)    __builtin_amdgcn_rcpf(x)
#define INV_2PI    0.15915494309189535f
#define NEG_L2_10K_O32 -0.41524101186092046f  // -log2(10000)/32

// 7-inst tanh-GELU: x - x/(1+e^{2z}), with 2z*log2e = x*(c1 + c2*x^2)
__device__ __forceinline__ float gelu_f(float x){
  float x2 = x * x;
  float t  = __builtin_fmaf(0.10294824f, x2, 2.3022079f);
  float e  = EXP2F(x * t);
  float r  = RCPF(1.0f + e);
  return __builtin_fmaf(-x, r, x);
}

__device__ __forceinline__ int pkh(float a, float b){
  fp16x2 p = __builtin_amdgcn_cvt_pkrtz(a, b);
  return __builtin_bit_cast(int, p);
}

__device__ __forceinline__ float wave_reduce(float v){
  #pragma unroll
  for (int s = 1; s < 64; s <<= 1) v += __shfl_xor(v, s, 64);
  return v;
}

// ---- K0: folded-weight prep + packed node records ----
//  w1tc[n][k],[192][224]: k<192 -> W1_top[k][n]; k=192..194 -> (W_in@W1_top)[k-192][n]; else 0
//  w1bc: same for W1_bot.  w2t[n][k] = W2[k][n]/32.
//  bias_c[n] = b1[n] + (b_in@(W1_top+W1_bot))[n]
//  pf[node] = {f0,f1,f2,0, p0,p1,p2,0} fp16 (16B) — single-line gather record
__global__ void k0_prep(const float* __restrict__ W_in, const float* __restrict__ b_in,
    const float* __restrict__ W1, const float* __restrict__ b1,
    const float* __restrict__ W2, const float* __restrict__ feat,
    const float* __restrict__ pos, int npts,
    _Float16* __restrict__ w1tc, _Float16* __restrict__ w1bc,
    _Float16* __restrict__ w2t, float* __restrict__ bias_c,
    _Float16* __restrict__ pf){
  int id = blockIdx.x * 256 + threadIdx.x;
  if (id < 73728){                      // A: transpose copy, coalesced reads
    int half_sel = id / 36864;
    int i = id - half_sel * 36864;
    int k = i / 192, n = i - k * 192;
    const float* Wh = W1 + half_sel * 36864;
    (half_sel ? w1bc : w1tc)[n*224 + k] = (_Float16)Wh[i];
  } else if (id < 84864){               // B: zero cols 195..223
    int i = id - 73728;                 // 2*192*29
    int half_sel = i / 5568;
    int j = i - half_sel * 5568;
    int n = j / 29, k = 195 + (j - n * 29);
    (half_sel ? w1bc : w1tc)[n*224 + k] = (_Float16)0.f;
  } else if (id < 121728){              // C: w2t transpose, coalesced reads
    int i = id - 84864;
    int k = i / 192, n = i - k * 192;
    w2t[n*192 + k] = (_Float16)(W2[i] * 0.03125f);
  } else if (id < 134016){              // D: bias_c, one wave per n
    int o = (id - 121728 - 12288 + 12288) >> 6;  // local wave id
    o = (id - 121728) >> 6;
    int lane = id & 63;
    float s = 0.f;
    #pragma unroll
    for (int u = 0; u < 3; u++){
      int m = lane + 64*u;
      s += b_in[m] * (W1[m*192 + o] + W1[(m+192)*192 + o]);
    }
    s = wave_reduce(s);
    if (lane == 0) bias_c[o] = s + b1[o];
  } else if (id < 207744){              // E: fold cols 192..194, one wave per (half,r,n)
    int o = (id - 134016) >> 6, lane = id & 63;
    int half_sel = o / 576;
    int rem = o - half_sel * 576;
    int r = rem / 192, n = rem - r * 192;
    const float* Wh = W1 + half_sel * 36864;
    float s = 0.f;
    #pragma unroll
    for (int u = 0; u < 3; u++){
      int m = lane + 64*u;
      s += W_in[r*192 + m] * Wh[m*192 + n];
    }
    s = wave_reduce(s);
    if (lane == 0) (half_sel ? w1bc : w1tc)[n*224 + 192 + r] = (_Float16)s;
  } else {                              // F: pack pf
    int n = id - 207744;
    if (n < npts){
      float f0 = feat[3*n], f1 = feat[3*n+1], f2 = feat[3*n+2];
      float p0 = pos[3*n],  p1 = pos[3*n+1],  p2 = pos[3*n+2];
      int4v v; v[0] = pkh(f0, f1); v[1] = pkh(f2, 0.f);
               v[2] = pkh(p0, p1); v[3] = pkh(p2, 0.f);
      *reinterpret_cast<int4v*>(pf + n*8) = v;
    }
  }
}

// ---- K1: a_dst[8192][192] (fp16) = embed(dst) @ w1bc + bias_c  (256thr, 128 blocks) ----
__global__ __launch_bounds__(256) void k1_dst(const int* __restrict__ dst_idx,
    const float* __restrict__ feat, const float* __restrict__ pos,
    const _Float16* __restrict__ w1bc, const float* __restrict__ bias_c,
    _Float16* __restrict__ a_dst){
  __shared__ _Float16 sA[64][SAW];
  __shared__ float sPos[64][3];
  __shared__ float sOmg[32];
  int blk = blockIdx.x, t = threadIdx.x;
  if (t < 32) sOmg[t] = EXP2F((float)t * NEG_L2_10K_O32) * INV_2PI;
  if (t < 64){
    int node = dst_idx[(blk*64 + t) * DEG];
    sPos[t][0] = pos[3*node]; sPos[t][1] = pos[3*node+1]; sPos[t][2] = pos[3*node+2];
  }
  if (t >= 192){
    int e = t - 192;
    int node = dst_idx[(blk*64 + e) * DEG];
    float f0 = feat[3*node], f1 = feat[3*node+1], f2 = feat[3*node+2];
    int4v v0; v0[0] = pkh(f0, f1); v0[1] = pkh(f2, 0.f); v0[2] = 0; v0[3] = 0;
    int4v z; z[0] = 0; z[1] = 0; z[2] = 0; z[3] = 0;
    *reinterpret_cast<int4v*>(&sA[e][192]) = v0;
    *reinterpret_cast<int4v*>(&sA[e][200]) = z;
    *reinterpret_cast<int4v*>(&sA[e][208]) = z;
    *reinterpret_cast<int4v*>(&sA[e][216]) = z;
  }
  __syncthreads();
  if (t < 192){
    int lane = t & 63, w = t >> 6;
    int r16 = lane & 15, g = lane >> 4;
    float om[8];
    #pragma unroll
    for (int j = 0; j < 8; j++) om[j] = sOmg[8*g + j];
    #pragma unroll
    for (int rr = 0; rr < 4; rr++){
      int row = r16 + rr*16;
      float p = sPos[row][w];
      int4v sv, cv;
      #pragma unroll
      for (int j = 0; j < 4; j++){
        float a0 = p * om[2*j], a1 = p * om[2*j+1];
        sv[j] = pkh(SIN_REV(a0), SIN_REV(a1));
        cv[j] = pkh(COS_REV(a0), COS_REV(a1));
      }
      int ch = w*8 + g;
      *reinterpret_cast<int4v*>(&sA[row][8*ch])     = sv;
      *reinterpret_cast<int4v*>(&sA[row][8*(ch+4)]) = cv;
    }
  }
  __syncthreads();
  int wave = t >> 6, lane = t & 63, ln15 = lane & 15, grp = lane >> 4;
  f32x4 acc[4][3];
  #pragma unroll
  for (int m = 0; m < 4; m++)
    #pragma unroll
    for (int n = 0; n < 3; n++) acc[m][n] = (f32x4){0.f, 0.f, 0.f, 0.f};
  #pragma unroll
  for (int k6 = 0; k6 < 7; k6++){
    half8 Af[4];
    #pragma unroll
    for (int m = 0; m < 4; m++)
      Af[m] = *reinterpret_cast<const half8*>(&sA[m*16 + ln15][k6*32 + grp*8]);
    #pragma unroll
    for (int n = 0; n < 3; n++){
      half8 Bf = *reinterpret_cast<const half8*>(w1bc + (wave*48 + n*16 + ln15)*224 + k6*32 + grp*8);
      #pragma unroll
      for (int m = 0; m < 4; m++)
        acc[m][n] = __builtin_amdgcn_mfma_f32_16x16x32_f16(Af[m], Bf, acc[m][n], 0, 0, 0);
    }
  }
  #pragma unroll
  for (int n = 0; n < 3; n++){
    int col = wave*48 + n*16 + ln15;
    float bias = bias_c[col];
    #pragma unroll
    for (int m = 0; m < 4; m++)
      #pragma unroll
      for (int r = 0; r < 4; r++)
        a_dst[(blk*64 + m*16 + grp*4 + r)*192 + col] = (_Float16)(acc[m][n][r] + bias);
  }
}

// ---- K2: 512-thr, 128-row tiles, waves 0-5 trig / 6-7 gather, ad-in-acc ----
__global__ __launch_bounds__(512) void k2_edge(const int* __restrict__ src_idx,
    const _Float16* __restrict__ pf, const _Float16* __restrict__ w1tc,
    const _Float16* __restrict__ a_dst, _Float16* __restrict__ S1){
  __shared__ _Float16 sA[128][SAW];   // 59.4 KB
  __shared__ float sPos[128][3];      // 1.5 KB
  int blk = blockIdx.x, t = threadIdx.x;
  int wv = t >> 6, lane = t & 63, ln15 = lane & 15, grp = lane >> 4;
  int e0 = blk * (NT*128), sn_base = blk * (NT*4);
  int mg = wv >> 2, cg = wv & 3;

  // per-lane omegas: freq = grp*8 + j (k6-invariant)
  float om8[8];
  #pragma unroll
  for (int j = 0; j < 8; j++)
    om8[j] = EXP2F((float)(grp*8 + j) * NEG_L2_10K_O32) * INV_2PI;

  int idxA[NT];
  half8 vcur, vnxt;
  if (wv >= 6){
    int grow = t - 384;
    #pragma unroll
    for (int tl = 0; tl < NT; tl++) idxA[tl] = src_idx[e0 + tl*128 + grow];
    vcur = *reinterpret_cast<const half8*>(pf + idxA[0]*8);
    int4v z; z[0] = 0; z[1] = 0; z[2] = 0; z[3] = 0;
    *reinterpret_cast<int4v*>(&sA[grow][200]) = z;
    *reinterpret_cast<int4v*>(&sA[grow][208]) = z;
    *reinterpret_cast<int4v*>(&sA[grow][216]) = z;
    int4v vi = __builtin_bit_cast(int4v, vcur);
    int4v fv; fv[0] = vi[0]; fv[1] = vi[1]; fv[2] = 0; fv[3] = 0;
    *reinterpret_cast<int4v*>(&sA[grow][192]) = fv;
    sPos[grow][0] = (float)vcur[4]; sPos[grow][1] = (float)vcur[5]; sPos[grow][2] = (float)vcur[6];
  }
  __syncthreads();

  for (int tl = 0; tl < NT; ++tl){
    // ---- phase 1: trig (wv<6) / stage feat + issue next gather (wv>=6) ----
    float ad[2][3];
    #pragma unroll
    for (int h = 0; h < 2; h++){
      int sn = sn_base + tl*4 + mg*2 + h;
      #pragma unroll
      for (int n = 0; n < 3; n++)
        ad[h][n] = (float)a_dst[sn*192 + cg*48 + n*16 + ln15];
    }
    if (wv < 6){
      int axis = wv >> 1, sub = wv & 1;
      #pragma unroll
      for (int rr = 0; rr < 4; rr++){
        int row = ln15 + rr*16 + sub*64;
        float p = sPos[row][axis];
        int4v sv, cv;
        #pragma unroll
        for (int j = 0; j < 4; j++){
          float a0 = p * om8[2*j], a1 = p * om8[2*j+1];
          sv[j] = pkh(SIN_REV(a0), SIN_REV(a1));
          cv[j] = pkh(COS_REV(a0), COS_REV(a1));
        }
        *reinterpret_cast<int4v*>(&sA[row][64*axis + 8*grp])      = sv;
        *reinterpret_cast<int4v*>(&sA[row][64*axis + 32 + 8*grp]) = cv;
      }
    } else {
      int grow = t - 384;
      if (tl > 0){
        int4v vi = __builtin_bit_cast(int4v, vcur);
        int4v fv; fv[0] = vi[0]; fv[1] = vi[1]; fv[2] = 0; fv[3] = 0;
        *reinterpret_cast<int4v*>(&sA[grow][192]) = fv;
      }
      if (tl + 1 < NT) vnxt = *reinterpret_cast<const half8*>(pf + idxA[tl+1]*8);
    }
    __syncthreads();
    // ---- phase 2: MFMA with acc init = ad (dst-add for free) ----
    f32x4 acc[4][3];
    #pragma unroll
    for (int m = 0; m < 4; m++)
      #pragma unroll
      for (int n = 0; n < 3; n++){
        float av = ad[m>>1][n];
        acc[m][n] = (f32x4){av, av, av, av};
      }
    #pragma unroll
    for (int k6 = 0; k6 < 7; k6++){
      half8 Af[4];
      #pragma unroll
      for (int m = 0; m < 4; m++)
        Af[m] = *reinterpret_cast<const half8*>(&sA[mg*64 + m*16 + ln15][k6*32 + grp*8]);
      #pragma unroll
      for (int n = 0; n < 3; n++){
        half8 Bf = *reinterpret_cast<const half8*>(w1tc + (cg*48 + n*16 + ln15)*224 + k6*32 + grp*8);
        #pragma unroll
        for (int m = 0; m < 4; m++)
          acc[m][n] = __builtin_amdgcn_mfma_f32_16x16x32_f16(Af[m], Bf, acc[m][n], 0, 0, 0);
      }
    }
    // epilogue: gelu + 16-row reduce per supernode half
    #pragma unroll
    for (int h = 0; h < 2; h++){
      int sn = sn_base + tl*4 + mg*2 + h;
      #pragma unroll
      for (int n = 0; n < 3; n++){
        float cs = 0.f;
        #pragma unroll
        for (int mm = 0; mm < 2; mm++){
          f32x4 a = acc[h*2 + mm][n];
          #pragma unroll
          for (int r = 0; r < 4; r++) cs += gelu_f(a[r]);
        }
        cs += __shfl_xor(cs, 16, 64);
        cs += __shfl_xor(cs, 32, 64);
        if (grp == 0)
          S1[sn*192 + cg*48 + n*16 + ln15] = (_Float16)cs;
      }
    }
    // stage next tile's pos (sPos unread in this phase)
    if (wv >= 6 && tl + 1 < NT){
      int grow = t - 384;
      sPos[grow][0] = (float)vnxt[4]; sPos[grow][1] = (float)vnxt[5]; sPos[grow][2] = (float)vnxt[6];
      vcur = vnxt;
    }
    __syncthreads();
  }
}

// ---- K3: out[8192][192] = S1 @ (W2/32) + b2 ----
__global__ __launch_bounds__(256) void k3_out(const _Float16* __restrict__ S1,
    const _Float16* __restrict__ w2t, const float* __restrict__ b2,
    float* __restrict__ out){
  int blk = blockIdx.x, t = threadIdx.x;
  int wave = t >> 6, lane = t & 63, ln15 = lane & 15, grp = lane >> 4;
  f32x4 acc[4][3];
  #pragma unroll
  for (int m = 0; m < 4; m++)
    #pragma unroll
    for (int n = 0; n < 3; n++) acc[m][n] = (f32x4){0.f, 0.f, 0.f, 0.f};
  #pragma unroll
  for (int k6 = 0; k6 < 6; k6++){
    half8 Af[4];
    #pragma unroll
    for (int m = 0; m < 4; m++)
      Af[m] = *reinterpret_cast<const half8*>(S1 + (blk*64 + m*16 + ln15)*192 + k6*32 + grp*8);
    #pragma unroll
    for (int n = 0; n < 3; n++){
      half8 Bf = *reinterpret_cast<const half8*>(w2t + (wave*48 + n*16 + ln15)*192 + k6*32 + grp*8);
      #pragma unroll
      for (int m = 0; m < 4; m++)
        acc[m][n] = __builtin_amdgcn_mfma_f32_16x16x32_f16(Af[m], Bf, acc[m][n], 0, 0, 0);
    }
  }
  #pragma unroll
  for (int n = 0; n < 3; n++){
    int col = wave*48 + n*16 + ln15;
    float bias = b2[col];
    #pragma unroll
    for (int m = 0; m < 4; m++)
      #pragma unroll
      for (int r = 0; r < 4; r++)
        out[(blk*64 + m*16 + grp*4 + r)*192 + col] = acc[m][n][r] + bias;
  }
}

extern "C" void kernel_launch(void* const* d_in, const int* in_sizes, int n_in,
                              void* d_out, int out_size, void* d_ws, size_t ws_size,
                              hipStream_t stream) {
  const float* feat   = (const float*)d_in[0];
  const float* pos    = (const float*)d_in[1];
  const int*   src_i  = (const int*)  d_in[2];
  const int*   dst_i  = (const int*)  d_in[3];
  const float* W_in   = (const float*)d_in[4];
  const float* b_in   = (const float*)d_in[5];
  const float* W1     = (const float*)d_in[6];
  const float* b1     = (const float*)d_in[7];
  const float* W2     = (const float*)d_in[8];
  const float* b2     = (const float*)d_in[9];
  float* out = (float*)d_out;
  int npts = in_sizes[0] / 3;

  char* ws = (char*)d_ws;
  _Float16* w1tc   = (_Float16*)(ws);                 // 192*224*2 =  86016 B
  _Float16* w1bc   = (_Float16*)(ws + 86016);         //              86016 B
  _Float16* w2t    = (_Float16*)(ws + 172032);        // 192*192*2 =  73728 B
  float*    bias_c = (float*)   (ws + 245760);        //                768 B
  _Float16* a_dst  = (_Float16*)(ws + 246528);        // 8192*192*2 = 3145728 B
  _Float16* S1     = (_Float16*)(ws + 3392256);       // 8192*192*2 = 3145728 B
  _Float16* pf     = (_Float16*)(ws + 6537984);       // npts*16   = 8000000 B
  // total ws use: ~14.54 MB

  int k0_grid = (207744 + npts + 255) / 256;
  k0_prep<<<k0_grid, 256, 0, stream>>>(W_in, b_in, W1, b1, W2, feat, pos, npts,
                                       w1tc, w1bc, w2t, bias_c, pf);
  k1_dst <<<128, 256, 0, stream>>>(dst_i, feat, pos, w1bc, bias_c, a_dst);
  k2_edge<<<512, 512, 0, stream>>>(src_i, pf, w1tc, a_dst, S1);
  k3_out <<<128, 256, 0, stream>>>(S1, w2t, b2, out);
}